// Round 4
// baseline (817.913 us; speedup 1.0000x reference)
//
#include <hip/hip_runtime.h>

// 13-branch fused Conv3d(2->13, k=5, SAME) + bias + clip(0,100)
// bf16 MFMA implicit GEMM, weight-shift reuse, z-persistent blocks with
// rolling 8-slot LDS plane window + register-staged prefetch.
// x: [16][2][64][64][64] f32, W: [13][2][5][5][5] f32, b: [13], out: [16][13][64][64][64] f32

typedef __attribute__((ext_vector_type(8))) short bf16x8;
typedef __attribute__((ext_vector_type(4))) float f32x4;

#define YB 8
#define YR 12              // YB + 4 halo
#define UPITCH 72          // bf16 elems per row (68 used: x=-2..65)
#define ROWB 144           // bytes per row
#define SLOTS 8            // rolling z-plane slots per ci
#define CISTRIDE 13824     // 8*12*144 bytes
#define SLOTSTRIDE 1728    // 12*144 bytes
#define ZSTEPS 8           // z-steps per block (ZB=2 each)

__device__ __forceinline__ unsigned f2bf(float f) {
    unsigned u = __builtin_bit_cast(unsigned, f);
    return (u + 0x7FFFu + ((u >> 16) & 1u)) >> 16;   // RNE bf16
}

__global__ __launch_bounds__(256, 2)
void conv13_roll(const float* __restrict__ X,
                 const float* __restrict__ W,
                 const float* __restrict__ Bv,
                 float* __restrict__ O) {
    __shared__ unsigned short lds[2 * SLOTS * YR * UPITCH];   // 27648 B

    const int tid = threadIdx.x;
    const int l   = tid & 63;
    const int wid = tid >> 6;
    const int g   = l >> 4;
    const int lx  = l & 15;
    const int yt = blockIdx.x;          // 0..7
    const int zc = blockIdx.y;          // 0..3
    const int b  = blockIdx.z;          // 0..15
    const int zlo = zc * 16;
    const int gy0 = yt * YB - 2;
    const int zz  = wid >> 1;           // wave's z within step
    const int yy0 = (wid & 1) * 4;      // wave's first y-row

    // ---- A: weight fragments (m=cout=lx, k-row r=4s+g), once per block ----
    unsigned wf[13][4];
    int cOffW[13], dzv[13];
    #pragma unroll
    for (int s = 0; s < 13; ++s) {
        int r  = 4 * s + g;
        int rc = (r < 50) ? r : 49;
        int ci = rc / 25, r2 = rc % 25, dz = r2 / 5, dy = r2 % 5;
        dzv[s]   = dz;
        cOffW[s] = ci * CISTRIDE + (yy0 + dy) * ROWB + 8 * lx;
        float w0 = 0.f, w1 = 0.f, w2 = 0.f, w3 = 0.f, w4 = 0.f;
        if (lx < 13 && r < 50) {
            const float* wr = W + ((lx * 2 + ci) * 25 + dz * 5 + dy) * 5;
            w0 = wr[0]; w1 = wr[1]; w2 = wr[2]; w3 = wr[3]; w4 = wr[4];
        }
        wf[s][0] = f2bf(w0) | (f2bf(w1) << 16);
        wf[s][1] = f2bf(w2) | (f2bf(w3) << 16);
        wf[s][2] = f2bf(w4);
        wf[s][3] = 0u;
    }
    float bvv[4];
    #pragma unroll
    for (int v = 0; v < 4; ++v) {
        int co = 4 * g + v;
        bvv[v] = (co < 13) ? Bv[co] : 0.0f;
    }

    // ---- initial fill: 6 planes (zlo-2 .. zlo+3) -> slots 0..5 ----
    for (int j = tid; j < 2592; j += 256) {        // 6pl*2ci*12ry*18q
        int q = j % 18, j2 = j / 18;
        int ry = j2 % 12, j3 = j2 / 12;
        int ci = j3 & 1, pl = j3 >> 1;             // 0..5
        int zi = zlo - 2 + pl, yi = gy0 + ry;
        int x0 = 4 * q - 2;
        float v0 = 0.f, v1 = 0.f, v2 = 0.f, v3 = 0.f;
        if ((unsigned)zi < 64u && (unsigned)yi < 64u) {
            const float* src = X + ((((size_t)b * 2 + ci) * 64 + zi) * 64 + yi) * 64;
            if ((unsigned)(x0 + 0) < 64u) v0 = src[x0 + 0];
            if ((unsigned)(x0 + 1) < 64u) v1 = src[x0 + 1];
            if ((unsigned)(x0 + 2) < 64u) v2 = src[x0 + 2];
            if ((unsigned)(x0 + 3) < 64u) v3 = src[x0 + 3];
        }
        unsigned* lp = (unsigned*)&lds[((ci * SLOTS + pl) * YR + ry) * UPITCH + 4 * q];
        lp[0] = f2bf(v0) | (f2bf(v1) << 16);
        lp[1] = f2bf(v2) | (f2bf(v3) << 16);
    }
    __syncthreads();

    // ---- z-step loop ----
    #pragma unroll 1
    for (int t = 0; t < ZSTEPS; ++t) {
        // A) issue prefetch loads for planes zlo+2t+4, +5 (slots (2t+6+pl)&7)
        float fv[16];
        if (t < ZSTEPS - 1) {
            #pragma unroll
            for (int k = 0; k < 4; ++k) {
                int j = tid + 256 * k;                 // 864 tasks: 2pl*2ci*12*18
                int q = j % 18, j2 = j / 18;
                int ry = j2 % 12, j3 = j2 / 12;
                int ci = j3 & 1, pl = j3 >> 1;
                int zi = zlo + 2 * t + 4 + pl, yi = gy0 + ry;
                int x0 = 4 * q - 2;
                bool rowok = (j < 864) && ((unsigned)zi < 64u) && ((unsigned)yi < 64u);
                const float* src = X + ((((size_t)b * 2 + ci) * 64 + zi) * 64 + yi) * 64;
                fv[4*k+0] = (rowok && (unsigned)(x0 + 0) < 64u) ? src[x0 + 0] : 0.f;
                fv[4*k+1] = (rowok && (unsigned)(x0 + 1) < 64u) ? src[x0 + 1] : 0.f;
                fv[4*k+2] = (rowok && (unsigned)(x0 + 2) < 64u) ? src[x0 + 2] : 0.f;
                fv[4*k+3] = (rowok && (unsigned)(x0 + 3) < 64u) ? src[x0 + 3] : 0.f;
            }
        }

        // B) compute step t: reads slots (2t+zz+dz)&7
        const int uw = 2 * t + zz;
        f32x4 acc[4][4];
        #pragma unroll
        for (int i = 0; i < 4; ++i)
            #pragma unroll
            for (int sh = 0; sh < 4; ++sh)
                acc[i][sh] = (f32x4){ bvv[0], bvv[1], bvv[2], bvv[3] };

        #pragma unroll
        for (int s = 0; s < 13; ++s) {
            int slot = (uw + dzv[s]) & 7;
            int ab = cOffW[s] + slot * SLOTSTRIDE;
            bf16x8 bb[4];
            #pragma unroll
            for (int i = 0; i < 4; ++i) {
                const char* p = (const char*)lds + (ab + i * ROWB);
                uint2 lo = *(const uint2*)p;
                uint2 hi = *(const uint2*)(p + 8);
                union { unsigned u[4]; bf16x8 v; } tmp;
                tmp.u[0] = lo.x; tmp.u[1] = lo.y; tmp.u[2] = hi.x; tmp.u[3] = hi.y;
                bb[i] = tmp.v;
            }
            unsigned a0 = wf[s][0], a1 = wf[s][1], a2 = wf[s][2], a3 = wf[s][3];
            #pragma unroll
            for (int sh = 0; sh < 4; ++sh) {
                if (sh) {
                    unsigned n1 = (a1 << 16) | (a0 >> 16);
                    unsigned n2 = (a2 << 16) | (a1 >> 16);
                    unsigned n3 = (a3 << 16) | (a2 >> 16);
                    a0 <<= 16; a1 = n1; a2 = n2; a3 = n3;
                }
                union { unsigned u[4]; bf16x8 v; } av;
                av.u[0] = a0; av.u[1] = a1; av.u[2] = a2; av.u[3] = a3;
                #pragma unroll
                for (int i = 0; i < 4; ++i)
                    acc[i][sh] = __builtin_amdgcn_mfma_f32_16x16x32_bf16(av.v, bb[i], acc[i][sh], 0, 0, 0);
            }
        }

        // C) epilogue: clip + float4 stores (lane covers x = 4lx..4lx+3)
        const int oz = zlo + 2 * t + zz;
        #pragma unroll
        for (int i = 0; i < 4; ++i) {
            int oy = yt * YB + yy0 + i;
            float* dst = O + (size_t)b * 3407872 + oz * 4096 + oy * 64 + 4 * lx;
            #pragma unroll
            for (int v = 0; v < 4; ++v) {
                int co = 4 * g + v;
                if (co < 13) {
                    f32x4 o4 = { fminf(fmaxf(acc[i][0][v], 0.0f), 100.0f),
                                 fminf(fmaxf(acc[i][1][v], 0.0f), 100.0f),
                                 fminf(fmaxf(acc[i][2][v], 0.0f), 100.0f),
                                 fminf(fmaxf(acc[i][3][v], 0.0f), 100.0f) };
                    *(f32x4*)(dst + (size_t)co * 262144) = o4;
                }
            }
        }

        // D) publish prefetched planes
        __syncthreads();
        if (t < ZSTEPS - 1) {
            #pragma unroll
            for (int k = 0; k < 4; ++k) {
                int j = tid + 256 * k;
                if (j < 864) {
                    int q = j % 18, j2 = j / 18;
                    int ry = j2 % 12, j3 = j2 / 12;
                    int ci = j3 & 1, pl = j3 >> 1;
                    int slot = (2 * t + 6 + pl) & 7;
                    unsigned* lp = (unsigned*)&lds[((ci * SLOTS + slot) * YR + ry) * UPITCH + 4 * q];
                    lp[0] = f2bf(fv[4*k+0]) | (f2bf(fv[4*k+1]) << 16);
                    lp[1] = f2bf(fv[4*k+2]) | (f2bf(fv[4*k+3]) << 16);
                }
            }
        }
        __syncthreads();
    }
}

extern "C" void kernel_launch(void* const* d_in, const int* in_sizes, int n_in,
                              void* d_out, int out_size, void* d_ws, size_t ws_size,
                              hipStream_t stream) {
    const float* X  = (const float*)d_in[0];
    const float* W  = (const float*)d_in[1];
    const float* Bv = (const float*)d_in[2];
    float* O = (float*)d_out;

    dim3 grid(8, 4, 16);   // yt, z-chunk, batch = 512 blocks (2/CU, all resident)
    conv13_roll<<<grid, 256, 0, stream>>>(X, W, Bv, O);
}

// Round 5
// 75.977 us; speedup vs baseline: 10.7652x; 10.7652x over previous
//
#include <hip/hip_runtime.h>

// 13-branch fused Conv3d(2->13, k=5, SAME) + bias + clip(0,100)
// Two-kernel plan:
//   K1: X fp32 -> zero-padded bf16 volume P[16][2][68][68][72] in d_ws.
//   K2: z-persistent blocks, rolling 8-slot LDS window filled by
//       global_load_lds (async DMA, no regs), weight-shift MFMA compute.
// Fallback (ws too small): round-3 single kernel.

typedef __attribute__((ext_vector_type(8))) short bf16x8;
typedef __attribute__((ext_vector_type(4))) float f32x4;
typedef unsigned short u16;

#define YB 8
#define YR 12
#define ROWB 144              // bytes per padded x-row (72 bf16)
#define SLOTB 2048            // LDS slot stride (1728 used + pad)
#define CIB 16384             // 8 slots per ci
#define ZSTEPS 8

#define PZ 68
#define PY 68
#define P_PLANE (PY * ROWB)                 // 9792 B
#define P_BYTES ((size_t)16 * 2 * PZ * P_PLANE)   // 21,307,392 B

__device__ __forceinline__ unsigned f2bf(float f) {
    unsigned u = __builtin_bit_cast(unsigned, f);
    return (u + 0x7FFFu + ((u >> 16) & 1u)) >> 16;   // RNE bf16
}

// ---------------- K1: pad + convert ----------------
__global__ __launch_bounds__(256)
void pad_bf16(const float* __restrict__ X, u16* __restrict__ P) {
    int idx = blockIdx.x * 256 + threadIdx.x;    // one per 4 xp elems
    int q = idx % 18;                            // xp chunk
    int r = idx / 18;
    int yp = r % 68; r /= 68;
    int zp = r % 68; r /= 68;
    int ci = r & 1;
    int b  = r >> 1;
    int z = zp - 2, y = yp - 2;
    bool rowok = ((unsigned)z < 64u) && ((unsigned)y < 64u);
    const float* src = X + ((((size_t)b * 2 + ci) * 64 + z) * 64 + y) * 64;
    u16 h[4];
    #pragma unroll
    for (int j = 0; j < 4; ++j) {
        int x = 4 * q + j - 2;
        float v = (rowok && (unsigned)x < 64u) ? src[x] : 0.0f;
        h[j] = (u16)f2bf(v);
    }
    *(ushort4*)(P + (size_t)idx * 4) = make_ushort4(h[0], h[1], h[2], h[3]);
}

// ---------------- K2: async rolling-window conv ----------------
__device__ __forceinline__ void gl16(const void* g, void* l) {
    __builtin_amdgcn_global_load_lds(
        (const __attribute__((address_space(1))) void*)g,
        (__attribute__((address_space(3))) void*)l, 16, 0, 0);
}

__global__ __launch_bounds__(256, 1)
void conv13_async(const u16* __restrict__ P, const float* __restrict__ W,
                  const float* __restrict__ Bv, float* __restrict__ O) {
    __shared__ char lds[2 * CIB];   // 32768 B

    const int tid = threadIdx.x;
    const int l   = tid & 63;
    const int wid = tid >> 6;
    const int g   = l >> 4;
    const int lx  = l & 15;
    const int yt = blockIdx.x;      // 0..7
    const int zc = blockIdx.y;      // 0..3
    const int b  = blockIdx.z;      // 0..15
    const int zlo = zc * 16;
    const int yp0 = yt * YB;        // padded-y of window start
    const int zz  = wid >> 1;
    const int yy0 = (wid & 1) * 4;

    // ---- A: weight fragments (m=cout=lx, k-row r=4s+g) ----
    unsigned wf[13][4];
    int cOff[13], dzv[13];
    #pragma unroll
    for (int s = 0; s < 13; ++s) {
        int r  = 4 * s + g;
        int rc = (r < 50) ? r : 49;
        int ci = rc / 25, r2 = rc % 25, dz = r2 / 5, dy = r2 % 5;
        dzv[s]  = dz;
        cOff[s] = ci * CIB + (yy0 + dy) * ROWB + 8 * lx;
        float w0 = 0.f, w1 = 0.f, w2 = 0.f, w3 = 0.f, w4 = 0.f;
        if (lx < 13 && r < 50) {
            const float* wr = W + ((lx * 2 + ci) * 25 + dz * 5 + dy) * 5;
            w0 = wr[0]; w1 = wr[1]; w2 = wr[2]; w3 = wr[3]; w4 = wr[4];
        }
        wf[s][0] = f2bf(w0) | (f2bf(w1) << 16);
        wf[s][1] = f2bf(w2) | (f2bf(w3) << 16);
        wf[s][2] = f2bf(w4);
        wf[s][3] = 0u;
    }
    float bvv[4];
    #pragma unroll
    for (int v = 0; v < 4; ++v) {
        int co = 4 * g + v;
        bvv[v] = (co < 13) ? Bv[co] : 0.0f;
    }

    const char* Pc = (const char*)P;
    int c1 = 64 + l; if (c1 > 107) c1 = 107;   // tail-clamped chunk

    // ---- initial fill: 12 regions (ci 0..1, planes zp=zlo..zlo+5 -> slots 0..5) ----
    for (int r = wid; r < 12; r += 4) {
        int ci = r / 6, pl = r % 6;
        const char* gb = Pc + (((size_t)(b * 2 + ci) * PZ + (zlo + pl)) * P_PLANE)
                            + (size_t)yp0 * ROWB;
        char* lb = lds + ci * CIB + pl * SLOTB;
        gl16(gb + 16 * l,  lb);
        gl16(gb + 16 * c1, lb + 1024);
    }
    __syncthreads();   // drains vmcnt -> DMA visible

    // ---- z-step loop ----
    #pragma unroll 1
    for (int t = 0; t < ZSTEPS; ++t) {
        // A) issue async DMA for step t+1 (slots (2t+6+pl)&7; disjoint from reads 2t..2t+5)
        if (t < ZSTEPS - 1) {
            int ci = wid >> 1, pl = wid & 1;
            int slot = (2 * t + 6 + pl) & 7;
            int zp = zlo + 2 * t + 6 + pl;
            const char* gb = Pc + (((size_t)(b * 2 + ci) * PZ + zp) * P_PLANE)
                                + (size_t)yp0 * ROWB;
            char* lb = lds + ci * CIB + slot * SLOTB;
            gl16(gb + 16 * l,  lb);
            gl16(gb + 16 * c1, lb + 1024);
        }

        // B) compute step t
        const int uw = 2 * t + zz;
        f32x4 acc[4][4];
        #pragma unroll
        for (int i = 0; i < 4; ++i)
            #pragma unroll
            for (int sh = 0; sh < 4; ++sh)
                acc[i][sh] = (f32x4){ bvv[0], bvv[1], bvv[2], bvv[3] };

        #pragma unroll
        for (int s = 0; s < 13; ++s) {
            int ab = cOff[s] + (((uw + dzv[s]) & 7) * SLOTB);
            bf16x8 bb[4];
            #pragma unroll
            for (int i = 0; i < 4; ++i) {
                const char* p = lds + ab + i * ROWB;
                uint2 lo = *(const uint2*)p;
                uint2 hi = *(const uint2*)(p + 8);
                union { unsigned u[4]; bf16x8 v; } tmp;
                tmp.u[0] = lo.x; tmp.u[1] = lo.y; tmp.u[2] = hi.x; tmp.u[3] = hi.y;
                bb[i] = tmp.v;
            }
            unsigned a0 = wf[s][0], a1 = wf[s][1], a2 = wf[s][2], a3 = wf[s][3];
            #pragma unroll
            for (int sh = 0; sh < 4; ++sh) {
                if (sh) {
                    unsigned n1 = (a1 << 16) | (a0 >> 16);
                    unsigned n2 = (a2 << 16) | (a1 >> 16);
                    unsigned n3 = (a3 << 16) | (a2 >> 16);
                    a0 <<= 16; a1 = n1; a2 = n2; a3 = n3;
                }
                union { unsigned u[4]; bf16x8 v; } av;
                av.u[0] = a0; av.u[1] = a1; av.u[2] = a2; av.u[3] = a3;
                #pragma unroll
                for (int i = 0; i < 4; ++i)
                    acc[i][sh] = __builtin_amdgcn_mfma_f32_16x16x32_bf16(av.v, bb[i], acc[i][sh], 0, 0, 0);
            }
        }

        // C) epilogue: clip + float4 stores
        const int oz = zlo + 2 * t + zz;
        #pragma unroll
        for (int i = 0; i < 4; ++i) {
            int oy = yt * YB + yy0 + i;
            float* dst = O + (size_t)b * 3407872 + oz * 4096 + oy * 64 + 4 * lx;
            #pragma unroll
            for (int v = 0; v < 4; ++v) {
                int co = 4 * g + v;
                if (co < 13) {
                    f32x4 o4 = { fminf(fmaxf(acc[i][0][v], 0.0f), 100.0f),
                                 fminf(fmaxf(acc[i][1][v], 0.0f), 100.0f),
                                 fminf(fmaxf(acc[i][2][v], 0.0f), 100.0f),
                                 fminf(fmaxf(acc[i][3][v], 0.0f), 100.0f) };
                    *(f32x4*)(dst + (size_t)co * 262144) = o4;
                }
            }
        }

        // D) one barrier: waits DMA (vmcnt) + orders next iter's writes after reads
        __syncthreads();
    }
}

// ---------------- Fallback: round-3 kernel (ws too small) ----------------
#define F_YR 12
#define F_UPITCH 72
#define F_ROWB 144

__global__ __launch_bounds__(256, 2)
void conv13_mfma_shift(const float* __restrict__ X,
                       const float* __restrict__ W,
                       const float* __restrict__ Bv,
                       float* __restrict__ O) {
    __shared__ unsigned short lds[144 * F_UPITCH];

    const int tid = threadIdx.x;
    const int l   = tid & 63;
    const int wid = tid >> 6;
    const int g   = l >> 4;
    const int lx  = l & 15;
    const int yt = blockIdx.x, zt = blockIdx.y, b = blockIdx.z;

    unsigned wf[13][4];
    int rowConst[13];
    #pragma unroll
    for (int s = 0; s < 13; ++s) {
        int r  = 4 * s + g;
        int rc = (r < 50) ? r : 49;
        int ci = rc / 25, r2 = rc % 25, dz = r2 / 5, dy = r2 % 5;
        rowConst[s] = (ci * 72 + dz * F_YR + dy) * F_ROWB;
        float w0 = 0.f, w1 = 0.f, w2 = 0.f, w3 = 0.f, w4 = 0.f;
        if (lx < 13 && r < 50) {
            const float* wr = W + ((lx * 2 + ci) * 25 + dz * 5 + dy) * 5;
            w0 = wr[0]; w1 = wr[1]; w2 = wr[2]; w3 = wr[3]; w4 = wr[4];
        }
        wf[s][0] = f2bf(w0) | (f2bf(w1) << 16);
        wf[s][1] = f2bf(w2) | (f2bf(w3) << 16);
        wf[s][2] = f2bf(w4);
        wf[s][3] = 0u;
    }

    const int gz0 = zt * 2 - 2, gy0 = yt * 8 - 2;
    for (int idx = tid; idx < 144 * 18; idx += 256) {
        int row = idx / 18, q = idx % 18;
        int ci = row / 72;
        int rz = (row / F_YR) % 6;
        int ry = row % F_YR;
        int zi = gz0 + rz, yi = gy0 + ry;
        float v0 = 0.f, v1 = 0.f, v2 = 0.f, v3 = 0.f;
        if ((unsigned)zi < 64u && (unsigned)yi < 64u) {
            const float* src = X + ((((size_t)b * 2 + ci) * 64 + zi) * 64 + yi) * 64;
            int x0 = 4 * q - 2;
            if ((unsigned)(x0 + 0) < 64u) v0 = src[x0 + 0];
            if ((unsigned)(x0 + 1) < 64u) v1 = src[x0 + 1];
            if ((unsigned)(x0 + 2) < 64u) v2 = src[x0 + 2];
            if ((unsigned)(x0 + 3) < 64u) v3 = src[x0 + 3];
        }
        unsigned* lp = (unsigned*)&lds[row * F_UPITCH + 4 * q];
        lp[0] = f2bf(v0) | (f2bf(v1) << 16);
        lp[1] = f2bf(v2) | (f2bf(v3) << 16);
    }

    int tileOff[4], ozv[4], oyv[4];
    #pragma unroll
    for (int i = 0; i < 4; ++i) {
        int t = wid * 4 + i, zz = t >> 3, yy = t & 7;
        tileOff[i] = (zz * F_YR + yy) * F_ROWB;
        ozv[i] = zt * 2 + zz;
        oyv[i] = yt * 8 + yy;
    }
    float bvv[4];
    #pragma unroll
    for (int v = 0; v < 4; ++v) {
        int co = 4 * g + v;
        bvv[v] = (co < 13) ? Bv[co] : 0.0f;
    }
    f32x4 acc[4][4];
    #pragma unroll
    for (int i = 0; i < 4; ++i)
        #pragma unroll
        for (int sh = 0; sh < 4; ++sh)
            acc[i][sh] = (f32x4){ bvv[0], bvv[1], bvv[2], bvv[3] };
    __syncthreads();

    #pragma unroll
    for (int s = 0; s < 13; ++s) {
        bf16x8 bb[4];
        #pragma unroll
        for (int i = 0; i < 4; ++i) {
            const char* p = (const char*)lds + (rowConst[s] + tileOff[i] + 8 * lx);
            uint2 lo = *(const uint2*)p;
            uint2 hi = *(const uint2*)(p + 8);
            union { unsigned u[4]; bf16x8 v; } tmp;
            tmp.u[0] = lo.x; tmp.u[1] = lo.y; tmp.u[2] = hi.x; tmp.u[3] = hi.y;
            bb[i] = tmp.v;
        }
        unsigned a0 = wf[s][0], a1 = wf[s][1], a2 = wf[s][2], a3 = wf[s][3];
        #pragma unroll
        for (int sh = 0; sh < 4; ++sh) {
            if (sh) {
                unsigned n1 = (a1 << 16) | (a0 >> 16);
                unsigned n2 = (a2 << 16) | (a1 >> 16);
                unsigned n3 = (a3 << 16) | (a2 >> 16);
                a0 <<= 16; a1 = n1; a2 = n2; a3 = n3;
            }
            union { unsigned u[4]; bf16x8 v; } av;
            av.u[0] = a0; av.u[1] = a1; av.u[2] = a2; av.u[3] = a3;
            #pragma unroll
            for (int i = 0; i < 4; ++i)
                acc[i][sh] = __builtin_amdgcn_mfma_f32_16x16x32_bf16(av.v, bb[i], acc[i][sh], 0, 0, 0);
        }
    }
    #pragma unroll
    for (int i = 0; i < 4; ++i) {
        float* dst = O + ((((size_t)b * 13) * 64 + ozv[i]) * 64 + oyv[i]) * 64 + 4 * lx;
        #pragma unroll
        for (int v = 0; v < 4; ++v) {
            int co = 4 * g + v;
            if (co < 13) {
                f32x4 o4 = { fminf(fmaxf(acc[i][0][v], 0.0f), 100.0f),
                             fminf(fmaxf(acc[i][1][v], 0.0f), 100.0f),
                             fminf(fmaxf(acc[i][2][v], 0.0f), 100.0f),
                             fminf(fmaxf(acc[i][3][v], 0.0f), 100.0f) };
                *(f32x4*)(dst + (size_t)co * 262144) = o4;
            }
        }
    }
}

extern "C" void kernel_launch(void* const* d_in, const int* in_sizes, int n_in,
                              void* d_out, int out_size, void* d_ws, size_t ws_size,
                              hipStream_t stream) {
    const float* X  = (const float*)d_in[0];
    const float* W  = (const float*)d_in[1];
    const float* Bv = (const float*)d_in[2];
    float* O = (float*)d_out;

    if (ws_size >= P_BYTES) {
        u16* P = (u16*)d_ws;
        pad_bf16<<<10404, 256, 0, stream>>>(X, P);               // 2,663,424 tasks
        conv13_async<<<dim3(8, 4, 16), 256, 0, stream>>>(P, W, Bv, O);
    } else {
        conv13_mfma_shift<<<dim3(8, 32, 16), 256, 0, stream>>>(X, W, Bv, O);
    }
}